// Round 9
// baseline (253.989 us; speedup 1.0000x reference)
//
#include <hip/hip_runtime.h>
#include <math.h>

// Problem constants (b=4, n=m=l=4096, d=512, fft_len=8192, t_len=2l-2=8190)
#define N_FFT   8192
#define SEQ     4096
#define NCH     512
#define TLEN    8190

__device__ __forceinline__ float2 cmul(float2 a, float2 b) {
    return make_float2(a.x * b.x - a.y * b.y, a.x * b.y + a.y * b.x);
}
__device__ __forceinline__ float2 cmulj(float2 a, float2 b) {   // a * conj(b)
    return make_float2(a.x * b.x + a.y * b.y, a.y * b.x - a.x * b.y);
}
__device__ __forceinline__ float2 cadd(float2 a, float2 b) {
    return make_float2(a.x + b.x, a.y + b.y);
}
__device__ __forceinline__ float2 csub(float2 a, float2 b) {
    return make_float2(a.x - b.x, a.y - b.y);
}

// W32^j = exp(-2*pi*i*j/32), j in [0,16)
constexpr float W32C[16] = {
    1.0f, 0.9807852804032304f, 0.9238795325112867f, 0.8314696123025452f,
    0.7071067811865476f, 0.5555702330196023f, 0.3826834323650898f, 0.1950903220161283f,
    0.0f, -0.1950903220161282f, -0.3826834323650897f, -0.5555702330196020f,
    -0.7071067811865475f, -0.8314696123025453f, -0.9238795325112867f, -0.9807852804032304f
};
constexpr float W32S[16] = {
    -0.0f, -0.1950903220161283f, -0.3826834323650898f, -0.5555702330196022f,
    -0.7071067811865476f, -0.8314696123025452f, -0.9238795325112867f, -0.9807852804032304f,
    -1.0f, -0.9807852804032304f, -0.9238795325112867f, -0.8314696123025453f,
    -0.7071067811865476f, -0.5555702330196022f, -0.3826834323650899f, -0.1950903220161286f
};

constexpr int BREV5[32] = {0,16,8,24,4,20,12,28,2,18,10,26,6,22,14,30,
                           1,17,9,25,5,21,13,29,3,19,11,27,7,23,15,31};
constexpr int BREV4[16] = {0,8,4,12,2,10,6,14,1,9,5,13,3,11,7,15};

__device__ __forceinline__ int brev3i(int b) {
    return ((b & 1) << 2) | (b & 2) | ((b & 4) >> 2);
}

// ---------------------------------------------------------------- reg FFTs ---
__device__ __forceinline__ void fft32_dif(float2 a[32]) {
#pragma unroll
    for (int s = 4; s >= 0; --s) {
        const int h = 1 << s;
#pragma unroll
        for (int g = 0; g < 32; g += 2 * h) {
#pragma unroll
            for (int i = 0; i < h; ++i) {
                float2 x0 = a[g + i], x1 = a[g + i + h];
                a[g + i] = cadd(x0, x1);
                float2 w = make_float2(W32C[i << (4 - s)], W32S[i << (4 - s)]);
                a[g + i + h] = cmul(csub(x0, x1), w);
            }
        }
    }
}

__device__ __forceinline__ void fft16_dif(float2 a[16]) {
#pragma unroll
    for (int s = 3; s >= 0; --s) {
        const int h = 1 << s;
#pragma unroll
        for (int g = 0; g < 16; g += 2 * h) {
#pragma unroll
            for (int i = 0; i < h; ++i) {
                float2 x0 = a[g + i], x1 = a[g + i + h];
                a[g + i] = cadd(x0, x1);
                float2 w = make_float2(W32C[i << (4 - s)], W32S[i << (4 - s)]);
                a[g + i + h] = cmul(csub(x0, x1), w);
            }
        }
    }
}

__device__ __forceinline__ void ifft16_dit(float2 a[16]) {
#pragma unroll
    for (int s = 0; s <= 3; ++s) {
        const int h = 1 << s;
#pragma unroll
        for (int g = 0; g < 16; g += 2 * h) {
#pragma unroll
            for (int i = 0; i < h; ++i) {
                float2 w = make_float2(W32C[i << (4 - s)], -W32S[i << (4 - s)]);
                float2 t = cmul(a[g + i + h], w);
                float2 x0 = a[g + i];
                a[g + i] = cadd(x0, t);
                a[g + i + h] = csub(x0, t);
            }
        }
    }
}

__device__ __forceinline__ void fft8_dif(float2 a[8]) {
#pragma unroll
    for (int s = 2; s >= 0; --s) {
        const int h = 1 << s;
#pragma unroll
        for (int g = 0; g < 8; g += 2 * h) {
#pragma unroll
            for (int i = 0; i < h; ++i) {
                float2 x0 = a[g + i], x1 = a[g + i + h];
                a[g + i] = cadd(x0, x1);
                int e = (i << (2 - s)) << 2;   // W8^m = W32^{4m}
                float2 w = make_float2(W32C[e], W32S[e]);
                a[g + i + h] = cmul(csub(x0, x1), w);
            }
        }
    }
}

// bank-conflict-reduced LDS slot, 32-row layout (tfft)
__device__ __forceinline__ int SLOT(int r, int c) {
    return (r << 8) + (c ^ ((c >> 4) & 7) ^ ((r & 1) << 3));
}
// LDS slot of frequency bin q after tfft forward stage C
__device__ __forceinline__ int ZADDR(int q) {
    return SLOT(q & 31, (((q >> 5) & 31) << 3) + brev3i((q >> 10) & 7));
}
// 16-row layout (conv)
__device__ __forceinline__ int SLOT16(int r, int c) {
    return (r << 8) + (c ^ ((c >> 4) & 7) ^ ((r & 1) << 3));
}

// ---------------------------------------------------------------- twiddles ---
__global__ __launch_bounds__(256) void twiddle_init(float2* __restrict__ tw) {
    int k = blockIdx.x * 256 + threadIdx.x;
    double th = -2.0 * 3.14159265358979323846 * (double)k / (double)N_FFT;
    tw[k] = make_float2((float)cos(th), (float)sin(th));
}

// ---------------------------------------------------------------- transposes -
// Fused input transposes.
// bid < 1024:  x[b][n][d] -> xT[pb][d][n]  (64n x 64d tiles, float4 loads)
// bid >= 1024: t[n][d] -> tT[dp][n] (zero-padded to 8192)
__global__ __launch_bounds__(256) void transpose_in(const float* __restrict__ x,
                                                    const float* __restrict__ t,
                                                    float2* __restrict__ xT,
                                                    float2* __restrict__ tT) {
    __shared__ float tX[64][65], tY[64][65];
    const int tid = threadIdx.x;
    if (blockIdx.x < 1024) {
        const int bid = blockIdx.x;        // [pb:2][dt:8][nt:64]
        const int pb = bid >> 9;
        const int dt = (bid >> 6) & 7;
        const int nt = bid & 63;
        const int d0 = dt << 6, n0 = nt << 6;
        const float* x0 = x + (size_t)(2 * pb) * SEQ * NCH;
        const float* x1 = x0 + (size_t)SEQ * NCH;
        {
            const int c4 = tid & 15, r16 = tid >> 4;   // 16 float4 cols, 16 rows
#pragma unroll
            for (int it = 0; it < 4; ++it) {
                int row = r16 + (it << 4);
                size_t off = (size_t)(n0 + row) * NCH + d0 + (c4 << 2);
                float4 v0 = *(const float4*)(x0 + off);
                float4 v1 = *(const float4*)(x1 + off);
                tX[row][(c4 << 2) + 0] = v0.x; tX[row][(c4 << 2) + 1] = v0.y;
                tX[row][(c4 << 2) + 2] = v0.z; tX[row][(c4 << 2) + 3] = v0.w;
                tY[row][(c4 << 2) + 0] = v1.x; tY[row][(c4 << 2) + 1] = v1.y;
                tY[row][(c4 << 2) + 2] = v1.z; tY[row][(c4 << 2) + 3] = v1.w;
            }
        }
        __syncthreads();
        {
            const int nc = tid & 63, dr4 = tid >> 6;
#pragma unroll
            for (int it = 0; it < 16; ++it) {
                int dr = dr4 + (it << 2);
                xT[(((size_t)(pb * NCH + d0 + dr)) << 12) + n0 + nc] =
                    make_float2(tX[nc][dr], tY[nc][dr]);
            }
        }
    } else {
        const int bid = blockIdx.x - 1024; // [nt:128][dpt:4]
        const int nt = bid >> 2, dpt = bid & 3;
        const int n0 = nt << 6, dp0 = dpt << 6;
        {
            const int c = tid & 63, r4 = tid >> 6;
#pragma unroll
            for (int it = 0; it < 16; ++it) {
                int row = r4 + (it << 2);
                int nn = n0 + row;
                float2 v = make_float2(0.f, 0.f);
                if (nn < TLEN)
                    v = *(const float2*)(t + (size_t)nn * NCH + ((dp0 + c) << 1));
                tX[row][c] = v.x;
                tY[row][c] = v.y;
            }
        }
        __syncthreads();
        {
            const int nc = tid & 63, dr4 = tid >> 6;
#pragma unroll
            for (int it = 0; it < 16; ++it) {
                int dr = dr4 + (it << 2);
                tT[(((size_t)(dp0 + dr)) << 13) + n0 + nc] =
                    make_float2(tX[nc][dr], tY[nc][dr]);
            }
        }
    }
}

// ---------------------------------------------------------------- t spectra --
// Monolithic 8192 FFT (32x32x8), channels d0=2*bid, d1=2*bid+1 packed, input
// from tT (coalesced). Emits parity-split spectrum in WAVE-CONTIGUOUS chunk
// layout: f2 position p = (q<<9) + 2*t + e holds bin for conv-thread t's
// a[j], j = 2q+e: kp = (t>>4) + ((t&15)<<4) + (BREV4[j]<<8). Prescaled 1/8192.
__global__ __launch_bounds__(256) void tfft3_kernel(const float2* __restrict__ tT,
                                                    const float2* __restrict__ tw,
                                                    float2* __restrict__ Tc) {
    __shared__ float2 z[N_FFT];
    const int tid = threadIdx.x;
    const int d0 = blockIdx.x * 2;
    const int d1 = d0 + 1;
    const float2* tp = tT + ((size_t)blockIdx.x << 13);

    float2 a[32];
#pragma unroll
    for (int n1 = 0; n1 < 32; ++n1)
        a[n1] = tp[(n1 << 8) + tid];
    fft32_dif(a);
    {   // twiddle w^k1, w = tw[tid]; even/odd incremental chains
        float2 w = tw[tid], w2 = cmul(w, w);
        float2 we = make_float2(1.f, 0.f), wo = w;
#pragma unroll
        for (int k1 = 0; k1 < 32; k1 += 2) {
            z[SLOT(k1, tid)]     = (k1 == 0) ? a[0] : cmul(a[BREV5[k1]], we);
            z[SLOT(k1 + 1, tid)] = cmul(a[BREV5[k1 + 1]], wo);
            we = cmul(we, w2); wo = cmul(wo, w2);
        }
    }
    __syncthreads();

    {   // step B
        const int r = tid >> 3, n2p = tid & 7;
#pragma unroll
        for (int n1p = 0; n1p < 32; ++n1p)
            a[n1p] = z[SLOT(r, (n1p << 3) + n2p)];
        fft32_dif(a);
        float2 wb = tw[n2p << 5], wb2 = cmul(wb, wb);
        float2 be = make_float2(1.f, 0.f), bo = wb;
#pragma unroll
        for (int k1p = 0; k1p < 32; k1p += 2) {
            z[SLOT(r, (k1p << 3) + n2p)]       = (k1p == 0) ? a[0] : cmul(a[BREV5[k1p]], be);
            z[SLOT(r, ((k1p + 1) << 3) + n2p)] = cmul(a[BREV5[k1p + 1]], bo);
            be = cmul(be, wb2); bo = cmul(bo, wb2);
        }
    }
    __syncthreads();

    // step C: 8-point FFTs
#pragma unroll
    for (int u = 0; u < 4; ++u) {
        int f = tid + (u << 8);
        int k1 = f >> 5, k1p = f & 31;
        float2 b[8];
#pragma unroll
        for (int e = 0; e < 8; ++e) b[e] = z[SLOT(k1, (k1p << 3) + e)];
        fft8_dif(b);
#pragma unroll
        for (int j = 0; j < 8; ++j) z[SLOT(k1, (k1p << 3) + j)] = b[j];
    }
    __syncthreads();

    // Hermitian unpack, iterated output-position-major (coalesced writes)
    const float sc = 0.5f / (float)N_FFT;   // fold in ifft 1/N
#pragma unroll
    for (int v = 0; v < 16; ++v) {
        int p = tid + (v << 8);                 // f2 position in [0,4096)
        int q   = p >> 9;
        int rem = p & 511;
        int t_  = rem >> 1, e = rem & 1;
        int j_  = (q << 1) + e;
        int kp  = (t_ >> 4) + ((t_ & 15) << 4) + (BREV4[j_] << 8);
#pragma unroll
        for (int par = 0; par < 2; ++par) {
            int k  = 2 * kp + par;
            int km = (N_FFT - k) & (N_FFT - 1);
            float2 A = z[ZADDR(k)];
            float2 B = z[ZADDR(km)];
            float2 Bj = make_float2(B.x, -B.y);
            float2 T0 = make_float2((A.x + Bj.x) * sc, (A.y + Bj.y) * sc);
            float2 dd = csub(A, Bj);
            float2 T1 = make_float2(dd.y * sc, -dd.x * sc);
            Tc[(size_t)d0 * N_FFT + (par << 12) + p] = T0;
            Tc[(size_t)d1 * N_FFT + (par << 12) + p] = T1;
        }
    }
}

// ---------------------------------------------------------------- main conv --
// One 512-thread block per channel d. Lower 256 threads: even-bin chain;
// upper 256: odd-bin chain, in two 32 KB LDS halves. Twiddle powers built
// with 4 independent running chains (dep depth 4), bases hoisted out of the
// pb loop. Tc read is wave-contiguous float4 (layout from tfft3).
__global__ __launch_bounds__(512, 4) void conv5_kernel(float2* __restrict__ xoT,
                                                       const float2* __restrict__ tw,
                                                       const float2* __restrict__ Tc) {
    __shared__ float2 z[2 * SEQ];      // 64 KB: [par][16 rows][256 cols]
    const int tid = threadIdx.x;
    const int par = tid >> 8;          // chain parity (thread half)
    const int t   = tid & 255;         // local lane within chain
    const int d   = blockIdx.x;
    float2* zb = z + (par << 12);

    // hoisted twiddle bases (shared by fwd/inv, both pb)
    const float2 wA1 = tw[2 * t];                  // W_4096^t
    const float2 wA2 = cmul(wA1, wA1);
    const float2 wA3 = cmul(wA2, wA1);
    const float2 wA4 = cmul(wA2, wA2);
    const float2 wB1 = tw[(t & 15) << 5];          // W_256^{n3}
    const float2 wB2 = cmul(wB1, wB1);
    const float2 wB3 = cmul(wB2, wB1);
    const float2 wB4 = cmul(wB2, wB2);

    float2 xr[16], a[16];
    {   // load pb=0 row (both halves read the same row; upper hits L1/L2)
        const float2* xp0 = xoT + ((size_t)d << 12);
#pragma unroll
        for (int n1 = 0; n1 < 16; ++n1)
            xr[n1] = xp0[(n1 << 8) + t];
    }

#pragma unroll
    for (int pb = 0; pb < 2; ++pb) {
        if (pb == 1) __syncthreads();    // combine-reads done before reuse

        // ---- stage A: regs (+modulate for odd chain), fft16, twiddle, -> LDS
        if (par == 0) {
#pragma unroll
            for (int n1 = 0; n1 < 16; ++n1) a[n1] = xr[n1];
        } else {
#pragma unroll
            for (int n1 = 0; n1 < 16; ++n1)
                a[n1] = cmul(xr[n1], tw[(n1 << 8) + t]);
        }
        fft16_dif(a);
        {
            float2 c0 = make_float2(1.f, 0.f), c1 = wA1, c2 = wA2, c3 = wA3;
#pragma unroll
            for (int k1 = 0; k1 < 16; k1 += 4) {
                zb[SLOT16(k1, t)]     = (k1 == 0) ? a[0] : cmul(a[BREV4[k1]], c0);
                zb[SLOT16(k1 + 1, t)] = cmul(a[BREV4[k1 + 1]], c1);
                zb[SLOT16(k1 + 2, t)] = cmul(a[BREV4[k1 + 2]], c2);
                zb[SLOT16(k1 + 3, t)] = cmul(a[BREV4[k1 + 3]], c3);
                if (k1 < 12) {
                    c0 = cmul(c0, wA4); c1 = cmul(c1, wA4);
                    c2 = cmul(c2, wA4); c3 = cmul(c3, wA4);
                }
            }
        }
        if (pb == 0) {                   // prefetch pb=1 row (hidden under LDS phases)
            const float2* xp1 = xoT + ((size_t)(NCH + d) << 12);
#pragma unroll
            for (int n1 = 0; n1 < 16; ++n1)
                xr[n1] = xp1[(n1 << 8) + t];
        }
        __syncthreads();                 // A writes are cross-wave

        // ---- stage B: FFT16 over n2 for (k1, n3)
        {
            const int k1 = t >> 4, n3 = t & 15;
#pragma unroll
            for (int n2 = 0; n2 < 16; ++n2)
                a[n2] = zb[SLOT16(k1, (n2 << 4) + n3)];
            fft16_dif(a);
            float2 c0 = make_float2(1.f, 0.f), c1 = wB1, c2 = wB2, c3 = wB3;
#pragma unroll
            for (int r1 = 0; r1 < 16; r1 += 4) {
                zb[SLOT16(k1, (r1 << 4) + n3)]       = (r1 == 0) ? a[0] : cmul(a[BREV4[r1]], c0);
                zb[SLOT16(k1, ((r1 + 1) << 4) + n3)] = cmul(a[BREV4[r1 + 1]], c1);
                zb[SLOT16(k1, ((r1 + 2) << 4) + n3)] = cmul(a[BREV4[r1 + 2]], c2);
                zb[SLOT16(k1, ((r1 + 3) << 4) + n3)] = cmul(a[BREV4[r1 + 3]], c3);
                if (r1 < 12) {
                    c0 = cmul(c0, wB4); c1 = cmul(c1, wB4);
                    c2 = cmul(c2, wB4); c3 = cmul(c3, wB4);
                }
            }
        }
        // B->C exchange stays inside tids [16*k1, 16*k1+15] (one wave)
        __builtin_amdgcn_sched_barrier(0);

        // ---- stage C fwd + pointwise (own parity plane) + stage C inverse
        {
            const int k1 = t >> 4, r1 = t & 15;
#pragma unroll
            for (int n3 = 0; n3 < 16; ++n3)
                a[n3] = zb[SLOT16(k1, (r1 << 4) + n3)];
            fft16_dif(a);
            const float4* tp = (const float4*)(Tc + ((size_t)d << 13) + (par << 12));
#pragma unroll
            for (int q = 0; q < 8; ++q) {
                float4 f4 = tp[(q << 8) + t];       // 16B/lane contiguous
                a[2 * q]     = cmul(a[2 * q],     make_float2(f4.x, f4.y));
                a[2 * q + 1] = cmul(a[2 * q + 1], make_float2(f4.z, f4.w));
            }
            ifft16_dit(a);               // DIF output order == DIT input order
#pragma unroll
            for (int n3 = 0; n3 < 16; ++n3)
                zb[SLOT16(k1, (r1 << 4) + n3)] = a[n3];
        }
        __builtin_amdgcn_sched_barrier(0);   // C->Binv: same 16-lane group

        // ---- stage B inverse
        {
            const int k1 = t >> 4, n3 = t & 15;
            float2 c0 = make_float2(1.f, 0.f), c1 = wB1, c2 = wB2, c3 = wB3;
#pragma unroll
            for (int r1 = 0; r1 < 16; r1 += 4) {
                float2 v0 = zb[SLOT16(k1, (r1 << 4) + n3)];
                float2 v1 = zb[SLOT16(k1, ((r1 + 1) << 4) + n3)];
                float2 v2 = zb[SLOT16(k1, ((r1 + 2) << 4) + n3)];
                float2 v3 = zb[SLOT16(k1, ((r1 + 3) << 4) + n3)];
                a[BREV4[r1]]     = (r1 == 0) ? v0 : cmulj(v0, c0);
                a[BREV4[r1 + 1]] = cmulj(v1, c1);
                a[BREV4[r1 + 2]] = cmulj(v2, c2);
                a[BREV4[r1 + 3]] = cmulj(v3, c3);
                if (r1 < 12) {
                    c0 = cmul(c0, wB4); c1 = cmul(c1, wB4);
                    c2 = cmul(c2, wB4); c3 = cmul(c3, wB4);
                }
            }
            ifft16_dit(a);
#pragma unroll
            for (int n2 = 0; n2 < 16; ++n2)
                zb[SLOT16(k1, (n2 << 4) + n3)] = a[n2];
        }
        __syncthreads();                 // Binv writes read cross-wave by Ainv

        // ---- stage A inverse (thread-private column slots)
        {
            float2 c0 = make_float2(1.f, 0.f), c1 = wA1, c2 = wA2, c3 = wA3;
#pragma unroll
            for (int k1 = 0; k1 < 16; k1 += 4) {
                float2 v0 = zb[SLOT16(k1, t)];
                float2 v1 = zb[SLOT16(k1 + 1, t)];
                float2 v2 = zb[SLOT16(k1 + 2, t)];
                float2 v3 = zb[SLOT16(k1 + 3, t)];
                a[BREV4[k1]]     = (k1 == 0) ? v0 : cmulj(v0, c0);
                a[BREV4[k1 + 1]] = cmulj(v1, c1);
                a[BREV4[k1 + 2]] = cmulj(v2, c2);
                a[BREV4[k1 + 3]] = cmulj(v3, c3);
                if (k1 < 12) {
                    c0 = cmul(c0, wA4); c1 = cmul(c1, wA4);
                    c2 = cmul(c2, wA4); c3 = cmul(c3, wA4);
                }
            }
            ifft16_dit(a);               // a[n1] = U_par[n1*256 + t]
        }
        __syncthreads();                 // all A-inv reads done before overwrite

        // ---- half exchange: par0 exports n1=8..15, par1 exports n1=0..7
        if (par == 0) {
#pragma unroll
            for (int n1 = 8; n1 < 16; ++n1)
                zb[((n1 - 8) << 8) + t] = a[n1];
        } else {
#pragma unroll
            for (int n1 = 0; n1 < 8; ++n1)
                zb[(n1 << 8) + t] = a[n1];
        }
        __syncthreads();

        // ---- combine o[n] = U_e[n] + conj(w[n])*U_o[n]; each half stores 8
        {
            float2* xp = xoT + ((size_t)(pb * NCH + d) << 12);
            if (par == 0) {
#pragma unroll
                for (int n1 = 0; n1 < 8; ++n1) {
                    int n = (n1 << 8) + t;
                    float2 uo = z[SEQ + (n1 << 8) + t];
                    xp[n] = cadd(a[n1], cmulj(uo, tw[n]));
                }
            } else {
#pragma unroll
                for (int n1 = 8; n1 < 16; ++n1) {
                    int n = (n1 << 8) + t;
                    float2 ue = z[((n1 - 8) << 8) + t];
                    xp[n] = cadd(ue, cmulj(a[n1], tw[n]));
                }
            }
        }
    }
}

// ---------------------------------------------------------------- transpose --
// oT[pb][d][n] (float2: {b=2pb, b=2pb+1}) -> out[b][n][d]. LDS-tiled 32d x 64n.
__global__ __launch_bounds__(256) void transpose_out(const float2* __restrict__ oT,
                                                     float* __restrict__ out) {
    __shared__ float2 tile[32][65];
    const int tid = threadIdx.x;
    const int bid = blockIdx.x;
    const int pb = bid >> 10;
    const int dt = (bid >> 6) & 15;
    const int nt = bid & 63;
    const int d0 = dt << 5, n0 = nt << 6;

    {
        const int nl = tid & 63, dl = tid >> 6;
#pragma unroll
        for (int i = 0; i < 8; ++i) {
            int dd = dl + (i << 2);
            tile[dd][nl] = oT[(((size_t)(pb * NCH + d0 + dd)) << 12) + n0 + nl];
        }
    }
    __syncthreads();
    {
        const int dl = tid & 31, ns = tid >> 5;
        float* o0 = out + (size_t)(2 * pb) * SEQ * NCH;
        float* o1 = o0 + (size_t)SEQ * NCH;
#pragma unroll
        for (int j = 0; j < 8; ++j) {
            int nn = n0 + ns + (j << 3);
            float2 v = tile[dl][ns + (j << 3)];
            o0[(size_t)nn * NCH + d0 + dl] = v.x;
            o1[(size_t)nn * NCH + d0 + dl] = v.y;
        }
    }
}

// =================== fallback path (small ws) ===============================
__global__ __launch_bounds__(256) void tfft2_kernel(const float* __restrict__ t,
                                                    const float2* __restrict__ tw,
                                                    float2* __restrict__ Tc) {
    __shared__ float2 z[N_FFT];
    const int tid = threadIdx.x;
    const int d0 = blockIdx.x * 2;
    const int d1 = d0 + 1;

    float2 a[32];
#pragma unroll
    for (int n1 = 0; n1 < 32; ++n1) {
        int n = (n1 << 8) + tid;
        float va = 0.f, vb = 0.f;
        if (n < TLEN) {
            va = t[(size_t)n * NCH + d0];
            vb = t[(size_t)n * NCH + d1];
        }
        a[n1] = make_float2(va, vb);
    }
    fft32_dif(a);
    {
        float2 w = tw[tid], w2 = cmul(w, w);
        float2 we = make_float2(1.f, 0.f), wo = w;
#pragma unroll
        for (int k1 = 0; k1 < 32; k1 += 2) {
            z[SLOT(k1, tid)]     = (k1 == 0) ? a[0] : cmul(a[BREV5[k1]], we);
            z[SLOT(k1 + 1, tid)] = cmul(a[BREV5[k1 + 1]], wo);
            we = cmul(we, w2); wo = cmul(wo, w2);
        }
    }
    __syncthreads();
    {
        const int r = tid >> 3, n2p = tid & 7;
#pragma unroll
        for (int n1p = 0; n1p < 32; ++n1p)
            a[n1p] = z[SLOT(r, (n1p << 3) + n2p)];
        fft32_dif(a);
        float2 wb = tw[n2p << 5], wb2 = cmul(wb, wb);
        float2 be = make_float2(1.f, 0.f), bo = wb;
#pragma unroll
        for (int k1p = 0; k1p < 32; k1p += 2) {
            z[SLOT(r, (k1p << 3) + n2p)]       = (k1p == 0) ? a[0] : cmul(a[BREV5[k1p]], be);
            z[SLOT(r, ((k1p + 1) << 3) + n2p)] = cmul(a[BREV5[k1p + 1]], bo);
            be = cmul(be, wb2); bo = cmul(bo, wb2);
        }
    }
    __syncthreads();
#pragma unroll
    for (int u = 0; u < 4; ++u) {
        int f = tid + (u << 8);
        int k1 = f >> 5, k1p = f & 31;
        float2 b[8];
#pragma unroll
        for (int e = 0; e < 8; ++e) b[e] = z[SLOT(k1, (k1p << 3) + e)];
        fft8_dif(b);
#pragma unroll
        for (int j = 0; j < 8; ++j) z[SLOT(k1, (k1p << 3) + j)] = b[j];
    }
    __syncthreads();

    const float sc = 0.5f / (float)N_FFT;
#pragma unroll
    for (int v = 0; v < 16; ++v) {
        int s = tid + (v << 8);
        int k1 = s >> 8, r1 = (s >> 4) & 15, j = s & 15;
        int kp = k1 + (r1 << 4) + (BREV4[j] << 8);
#pragma unroll
        for (int par = 0; par < 2; ++par) {
            int k  = 2 * kp + par;
            int km = (N_FFT - k) & (N_FFT - 1);
            float2 A = z[ZADDR(k)];
            float2 B = z[ZADDR(km)];
            float2 Bj = make_float2(B.x, -B.y);
            float2 T0 = make_float2((A.x + Bj.x) * sc, (A.y + Bj.y) * sc);
            float2 dd = csub(A, Bj);
            float2 T1 = make_float2(dd.y * sc, -dd.x * sc);
            Tc[(size_t)d0 * N_FFT + (par << 12) + s] = T0;
            Tc[(size_t)d1 * N_FFT + (par << 12) + s] = T1;
        }
    }
}

template<bool OT>
__global__ __launch_bounds__(256, 4) void conv3_kernel(const float* __restrict__ x,
                                                       const float2* __restrict__ tw,
                                                       const float2* __restrict__ Tc,
                                                       float2* __restrict__ oT,
                                                       float* __restrict__ out) {
    __shared__ float2 z[SEQ];
    const int tid = threadIdx.x;
    const int sb = (blockIdx.x & 7) * 128 + (blockIdx.x >> 3);
    const int d  = sb >> 1;
    const int pb = sb & 1;

    const float* x0 = x + (size_t)(2 * pb) * SEQ * NCH + d;
    const float* x1 = x0 + (size_t)SEQ * NCH;

    float2 xr[16], a[16], ie[16];
#pragma unroll
    for (int n1 = 0; n1 < 16; ++n1) {
        int n = (n1 << 8) + tid;
        xr[n1] = make_float2(x0[(size_t)n * NCH], x1[(size_t)n * NCH]);
    }

#pragma unroll
    for (int par = 0; par < 2; ++par) {
        if (par == 1) __syncthreads();

        if (par == 0) {
#pragma unroll
            for (int n1 = 0; n1 < 16; ++n1) a[n1] = xr[n1];
        } else {
#pragma unroll
            for (int n1 = 0; n1 < 16; ++n1) {
                int n = (n1 << 8) + tid;
                a[n1] = cmul(xr[n1], tw[n]);
            }
        }
        fft16_dif(a);
        {
            float2 w = tw[2 * tid], w2 = cmul(w, w);
            float2 we = make_float2(1.f, 0.f), wo = w;
#pragma unroll
            for (int k1 = 0; k1 < 16; k1 += 2) {
                z[SLOT16(k1, tid)]     = (k1 == 0) ? a[0] : cmul(a[BREV4[k1]], we);
                z[SLOT16(k1 + 1, tid)] = cmul(a[BREV4[k1 + 1]], wo);
                we = cmul(we, w2); wo = cmul(wo, w2);
            }
        }
        __syncthreads();
        {
            const int k1 = tid >> 4, n3 = tid & 15;
#pragma unroll
            for (int n2 = 0; n2 < 16; ++n2)
                a[n2] = z[SLOT16(k1, (n2 << 4) + n3)];
            fft16_dif(a);
            float2 wb = tw[n3 << 5], wb2 = cmul(wb, wb);
            float2 be = make_float2(1.f, 0.f), bo = wb;
#pragma unroll
            for (int r1 = 0; r1 < 16; r1 += 2) {
                z[SLOT16(k1, (r1 << 4) + n3)]       = (r1 == 0) ? a[0] : cmul(a[BREV4[r1]], be);
                z[SLOT16(k1, ((r1 + 1) << 4) + n3)] = cmul(a[BREV4[r1 + 1]], bo);
                be = cmul(be, wb2); bo = cmul(bo, wb2);
            }
        }
        __syncthreads();
        {
            const int k1 = tid >> 4, r1 = tid & 15;
#pragma unroll
            for (int n3 = 0; n3 < 16; ++n3)
                a[n3] = z[SLOT16(k1, (r1 << 4) + n3)];
            fft16_dif(a);
            const float4* tp = (const float4*)(Tc + ((size_t)d << 13) + (par << 12) + (tid << 4));
#pragma unroll
            for (int q = 0; q < 8; ++q) {
                float4 f4 = tp[q];
                a[2 * q]     = cmul(a[2 * q],     make_float2(f4.x, f4.y));
                a[2 * q + 1] = cmul(a[2 * q + 1], make_float2(f4.z, f4.w));
            }
            ifft16_dit(a);
#pragma unroll
            for (int n3 = 0; n3 < 16; ++n3)
                z[SLOT16(k1, (r1 << 4) + n3)] = a[n3];
        }
        __syncthreads();
        {
            const int k1 = tid >> 4, n3 = tid & 15;
            float2 wb = tw[n3 << 5], wb2 = cmul(wb, wb);
            float2 be = make_float2(1.f, 0.f), bo = wb;
#pragma unroll
            for (int r1 = 0; r1 < 16; r1 += 2) {
                float2 v0 = z[SLOT16(k1, (r1 << 4) + n3)];
                float2 v1 = z[SLOT16(k1, ((r1 + 1) << 4) + n3)];
                a[BREV4[r1]]     = (r1 == 0) ? v0 : cmulj(v0, be);
                a[BREV4[r1 + 1]] = cmulj(v1, bo);
                be = cmul(be, wb2); bo = cmul(bo, wb2);
            }
            ifft16_dit(a);
#pragma unroll
            for (int n2 = 0; n2 < 16; ++n2)
                z[SLOT16(k1, (n2 << 4) + n3)] = a[n2];
        }
        __syncthreads();
        {
            float2 w = tw[2 * tid], w2 = cmul(w, w);
            float2 we = make_float2(1.f, 0.f), wo = w;
#pragma unroll
            for (int k1 = 0; k1 < 16; k1 += 2) {
                float2 v0 = z[SLOT16(k1, tid)];
                float2 v1 = z[SLOT16(k1 + 1, tid)];
                a[BREV4[k1]]     = (k1 == 0) ? v0 : cmulj(v0, we);
                a[BREV4[k1 + 1]] = cmulj(v1, wo);
                we = cmul(we, w2); wo = cmul(wo, w2);
            }
            ifft16_dit(a);
        }

        if (par == 0) {
#pragma unroll
            for (int n1 = 0; n1 < 16; ++n1) ie[n1] = a[n1];
        } else {
            if constexpr (OT) {
                float2* op = oT + (((size_t)(pb * NCH + d)) << 12);
#pragma unroll
                for (int n1 = 0; n1 < 16; ++n1) {
                    int n = (n1 << 8) + tid;
                    op[n] = cadd(ie[n1], cmulj(a[n1], tw[n]));
                }
            } else {
                float* o0 = out + (size_t)(2 * pb) * SEQ * NCH + d;
                float* o1 = o0 + (size_t)SEQ * NCH;
#pragma unroll
                for (int n1 = 0; n1 < 16; ++n1) {
                    int n = (n1 << 8) + tid;
                    float2 o = cadd(ie[n1], cmulj(a[n1], tw[n]));
                    o0[(size_t)n * NCH] = o.x;
                    o1[(size_t)n * NCH] = o.y;
                }
            }
        }
    }
}

extern "C" void kernel_launch(void* const* d_in, const int* in_sizes, int n_in,
                              void* d_out, int out_size, void* d_ws, size_t ws_size,
                              hipStream_t stream) {
    (void)in_sizes; (void)n_in; (void)out_size;
    const float* x = (const float*)d_in[0];
    const float* t = (const float*)d_in[1];
    float* out = (float*)d_out;

    float2* tw  = (float2*)d_ws;                   // 8192 f2 = 64 KB
    float2* Tc  = tw + N_FFT;                      // 512*8192 f2 = 33.55 MB
    float2* xoT = Tc + (size_t)NCH * N_FFT;        // 2*512*4096 f2 = 33.55 MB
    float2* tT  = xoT + 2ull * NCH * SEQ;          // 256*8192 f2 = 16.78 MB

    const size_t need_full = sizeof(float2) * ((size_t)N_FFT + (size_t)NCH * N_FFT
                                               + 2ull * NCH * SEQ
                                               + 256ull * N_FFT);   // ~84 MB
    const size_t need_ot   = sizeof(float2) * ((size_t)N_FFT + (size_t)NCH * N_FFT
                                               + 2ull * NCH * SEQ); // ~67.2 MB

    twiddle_init<<<N_FFT / 256, 256, 0, stream>>>(tw);
    if (ws_size >= need_full) {
        transpose_in<<<1536, 256, 0, stream>>>(x, t, xoT, tT);
        tfft3_kernel<<<NCH / 2, 256, 0, stream>>>(tT, tw, Tc);
        conv5_kernel<<<NCH, 512, 0, stream>>>(xoT, tw, Tc);
        transpose_out<<<2048, 256, 0, stream>>>(xoT, out);
    } else if (ws_size >= need_ot) {
        tfft2_kernel<<<NCH / 2, 256, 0, stream>>>(t, tw, Tc);
        conv3_kernel<true><<<1024, 256, 0, stream>>>(x, tw, Tc, xoT, out);
        transpose_out<<<2048, 256, 0, stream>>>(xoT, out);
    } else {
        tfft2_kernel<<<NCH / 2, 256, 0, stream>>>(t, tw, Tc);
        conv3_kernel<false><<<1024, 256, 0, stream>>>(x, tw, Tc, nullptr, out);
    }
}

// Round 10
// 102.322 us; speedup vs baseline: 2.4823x; 2.4823x over previous
//
#include <hip/hip_runtime.h>
#include <math.h>

// Problem constants (b=4, n=m=l=4096, d=512, fft_len=8192, t_len=2l-2=8190)
#define N_FFT   8192
#define SEQ     4096
#define NCH     512
#define TLEN    8190

__device__ __forceinline__ float2 cmul(float2 a, float2 b) {
    return make_float2(a.x * b.x - a.y * b.y, a.x * b.y + a.y * b.x);
}
__device__ __forceinline__ float2 cmulj(float2 a, float2 b) {   // a * conj(b)
    return make_float2(a.x * b.x + a.y * b.y, a.y * b.x - a.x * b.y);
}
__device__ __forceinline__ float2 cadd(float2 a, float2 b) {
    return make_float2(a.x + b.x, a.y + b.y);
}
__device__ __forceinline__ float2 csub(float2 a, float2 b) {
    return make_float2(a.x - b.x, a.y - b.y);
}

// W32^j = exp(-2*pi*i*j/32), j in [0,16)
constexpr float W32C[16] = {
    1.0f, 0.9807852804032304f, 0.9238795325112867f, 0.8314696123025452f,
    0.7071067811865476f, 0.5555702330196023f, 0.3826834323650898f, 0.1950903220161283f,
    0.0f, -0.1950903220161282f, -0.3826834323650897f, -0.5555702330196020f,
    -0.7071067811865475f, -0.8314696123025453f, -0.9238795325112867f, -0.9807852804032304f
};
constexpr float W32S[16] = {
    -0.0f, -0.1950903220161283f, -0.3826834323650898f, -0.5555702330196022f,
    -0.7071067811865476f, -0.8314696123025452f, -0.9238795325112867f, -0.9807852804032304f,
    -1.0f, -0.9807852804032304f, -0.9238795325112867f, -0.8314696123025453f,
    -0.7071067811865476f, -0.5555702330196022f, -0.3826834323650899f, -0.1950903220161286f
};

constexpr int BREV5[32] = {0,16,8,24,4,20,12,28,2,18,10,26,6,22,14,30,
                           1,17,9,25,5,21,13,29,3,19,11,27,7,23,15,31};
constexpr int BREV4[16] = {0,8,4,12,2,10,6,14,1,9,5,13,3,11,7,15};

__device__ __forceinline__ int brev3i(int b) {
    return ((b & 1) << 2) | (b & 2) | ((b & 4) >> 2);
}

// ---------------------------------------------------------------- reg FFTs ---
__device__ __forceinline__ void fft32_dif(float2 a[32]) {
#pragma unroll
    for (int s = 4; s >= 0; --s) {
        const int h = 1 << s;
#pragma unroll
        for (int g = 0; g < 32; g += 2 * h) {
#pragma unroll
            for (int i = 0; i < h; ++i) {
                float2 x0 = a[g + i], x1 = a[g + i + h];
                a[g + i] = cadd(x0, x1);
                float2 w = make_float2(W32C[i << (4 - s)], W32S[i << (4 - s)]);
                a[g + i + h] = cmul(csub(x0, x1), w);
            }
        }
    }
}

__device__ __forceinline__ void fft16_dif(float2 a[16]) {
#pragma unroll
    for (int s = 3; s >= 0; --s) {
        const int h = 1 << s;
#pragma unroll
        for (int g = 0; g < 16; g += 2 * h) {
#pragma unroll
            for (int i = 0; i < h; ++i) {
                float2 x0 = a[g + i], x1 = a[g + i + h];
                a[g + i] = cadd(x0, x1);
                float2 w = make_float2(W32C[i << (4 - s)], W32S[i << (4 - s)]);
                a[g + i + h] = cmul(csub(x0, x1), w);
            }
        }
    }
}

__device__ __forceinline__ void ifft16_dit(float2 a[16]) {
#pragma unroll
    for (int s = 0; s <= 3; ++s) {
        const int h = 1 << s;
#pragma unroll
        for (int g = 0; g < 16; g += 2 * h) {
#pragma unroll
            for (int i = 0; i < h; ++i) {
                float2 w = make_float2(W32C[i << (4 - s)], -W32S[i << (4 - s)]);
                float2 t = cmul(a[g + i + h], w);
                float2 x0 = a[g + i];
                a[g + i] = cadd(x0, t);
                a[g + i + h] = csub(x0, t);
            }
        }
    }
}

__device__ __forceinline__ void fft8_dif(float2 a[8]) {
#pragma unroll
    for (int s = 2; s >= 0; --s) {
        const int h = 1 << s;
#pragma unroll
        for (int g = 0; g < 8; g += 2 * h) {
#pragma unroll
            for (int i = 0; i < h; ++i) {
                float2 x0 = a[g + i], x1 = a[g + i + h];
                a[g + i] = cadd(x0, x1);
                int e = (i << (2 - s)) << 2;   // W8^m = W32^{4m}
                float2 w = make_float2(W32C[e], W32S[e]);
                a[g + i + h] = cmul(csub(x0, x1), w);
            }
        }
    }
}

// bank-conflict-reduced LDS slot, 32-row layout (tfft)
__device__ __forceinline__ int SLOT(int r, int c) {
    return (r << 8) + (c ^ ((c >> 4) & 7) ^ ((r & 1) << 3));
}
// LDS slot of frequency bin q after tfft forward stage C
__device__ __forceinline__ int ZADDR(int q) {
    return SLOT(q & 31, (((q >> 5) & 31) << 3) + brev3i((q >> 10) & 7));
}
// 16-row layout (conv)
__device__ __forceinline__ int SLOT16(int r, int c) {
    return (r << 8) + (c ^ ((c >> 4) & 7) ^ ((r & 1) << 3));
}

// ---------------------------------------------------------------- twiddles ---
__global__ __launch_bounds__(256) void twiddle_init(float2* __restrict__ tw) {
    int k = blockIdx.x * 256 + threadIdx.x;
    double th = -2.0 * 3.14159265358979323846 * (double)k / (double)N_FFT;
    tw[k] = make_float2((float)cos(th), (float)sin(th));
}

// ---------------------------------------------------------------- transposes -
// Fused input transposes.
// bid < 1024:  x[b][n][d] -> xT[pb][d][n]  (64n x 64d tiles, float4 loads)
// bid >= 1024: t[n][d] -> tT[dp][n] (zero-padded to 8192)
__global__ __launch_bounds__(256) void transpose_in(const float* __restrict__ x,
                                                    const float* __restrict__ t,
                                                    float2* __restrict__ xT,
                                                    float2* __restrict__ tT) {
    __shared__ float tX[64][65], tY[64][65];
    const int tid = threadIdx.x;
    if (blockIdx.x < 1024) {
        const int bid = blockIdx.x;        // [pb:2][dt:8][nt:64]
        const int pb = bid >> 9;
        const int dt = (bid >> 6) & 7;
        const int nt = bid & 63;
        const int d0 = dt << 6, n0 = nt << 6;
        const float* x0 = x + (size_t)(2 * pb) * SEQ * NCH;
        const float* x1 = x0 + (size_t)SEQ * NCH;
        {
            const int c4 = tid & 15, r16 = tid >> 4;   // 16 float4 cols, 16 rows
#pragma unroll
            for (int it = 0; it < 4; ++it) {
                int row = r16 + (it << 4);
                size_t off = (size_t)(n0 + row) * NCH + d0 + (c4 << 2);
                float4 v0 = *(const float4*)(x0 + off);
                float4 v1 = *(const float4*)(x1 + off);
                tX[row][(c4 << 2) + 0] = v0.x; tX[row][(c4 << 2) + 1] = v0.y;
                tX[row][(c4 << 2) + 2] = v0.z; tX[row][(c4 << 2) + 3] = v0.w;
                tY[row][(c4 << 2) + 0] = v1.x; tY[row][(c4 << 2) + 1] = v1.y;
                tY[row][(c4 << 2) + 2] = v1.z; tY[row][(c4 << 2) + 3] = v1.w;
            }
        }
        __syncthreads();
        {
            const int nc = tid & 63, dr4 = tid >> 6;
#pragma unroll
            for (int it = 0; it < 16; ++it) {
                int dr = dr4 + (it << 2);
                xT[(((size_t)(pb * NCH + d0 + dr)) << 12) + n0 + nc] =
                    make_float2(tX[nc][dr], tY[nc][dr]);
            }
        }
    } else {
        const int bid = blockIdx.x - 1024; // [nt:128][dpt:4]
        const int nt = bid >> 2, dpt = bid & 3;
        const int n0 = nt << 6, dp0 = dpt << 6;
        {
            const int c = tid & 63, r4 = tid >> 6;
#pragma unroll
            for (int it = 0; it < 16; ++it) {
                int row = r4 + (it << 2);
                int nn = n0 + row;
                float2 v = make_float2(0.f, 0.f);
                if (nn < TLEN)
                    v = *(const float2*)(t + (size_t)nn * NCH + ((dp0 + c) << 1));
                tX[row][c] = v.x;
                tY[row][c] = v.y;
            }
        }
        __syncthreads();
        {
            const int nc = tid & 63, dr4 = tid >> 6;
#pragma unroll
            for (int it = 0; it < 16; ++it) {
                int dr = dr4 + (it << 2);
                tT[(((size_t)(dp0 + dr)) << 13) + n0 + nc] =
                    make_float2(tX[nc][dr], tY[nc][dr]);
            }
        }
    }
}

// ---------------------------------------------------------------- t spectra --
// Monolithic 8192 FFT (32x32x8), channels d0=2*bid, d1=2*bid+1 packed, input
// from tT (coalesced). Emits parity-split spectrum in WAVE-CONTIGUOUS chunk
// layout: f2 position p = (q<<9) + 2*t + e holds bin for conv-thread t's
// a[j], j = 2q+e: kp = (t>>4) + ((t&15)<<4) + (BREV4[j]<<8). Prescaled 1/8192.
__global__ __launch_bounds__(256) void tfft3_kernel(const float2* __restrict__ tT,
                                                    const float2* __restrict__ tw,
                                                    float2* __restrict__ Tc) {
    __shared__ float2 z[N_FFT];
    const int tid = threadIdx.x;
    const int d0 = blockIdx.x * 2;
    const int d1 = d0 + 1;
    const float2* tp = tT + ((size_t)blockIdx.x << 13);

    float2 a[32];
#pragma unroll
    for (int n1 = 0; n1 < 32; ++n1)
        a[n1] = tp[(n1 << 8) + tid];
    fft32_dif(a);
    {   // twiddle w^k1, w = tw[tid]; even/odd incremental chains
        float2 w = tw[tid], w2 = cmul(w, w);
        float2 we = make_float2(1.f, 0.f), wo = w;
#pragma unroll
        for (int k1 = 0; k1 < 32; k1 += 2) {
            z[SLOT(k1, tid)]     = (k1 == 0) ? a[0] : cmul(a[BREV5[k1]], we);
            z[SLOT(k1 + 1, tid)] = cmul(a[BREV5[k1 + 1]], wo);
            we = cmul(we, w2); wo = cmul(wo, w2);
        }
    }
    __syncthreads();

    {   // step B
        const int r = tid >> 3, n2p = tid & 7;
#pragma unroll
        for (int n1p = 0; n1p < 32; ++n1p)
            a[n1p] = z[SLOT(r, (n1p << 3) + n2p)];
        fft32_dif(a);
        float2 wb = tw[n2p << 5], wb2 = cmul(wb, wb);
        float2 be = make_float2(1.f, 0.f), bo = wb;
#pragma unroll
        for (int k1p = 0; k1p < 32; k1p += 2) {
            z[SLOT(r, (k1p << 3) + n2p)]       = (k1p == 0) ? a[0] : cmul(a[BREV5[k1p]], be);
            z[SLOT(r, ((k1p + 1) << 3) + n2p)] = cmul(a[BREV5[k1p + 1]], bo);
            be = cmul(be, wb2); bo = cmul(bo, wb2);
        }
    }
    __syncthreads();

    // step C: 8-point FFTs
#pragma unroll
    for (int u = 0; u < 4; ++u) {
        int f = tid + (u << 8);
        int k1 = f >> 5, k1p = f & 31;
        float2 b[8];
#pragma unroll
        for (int e = 0; e < 8; ++e) b[e] = z[SLOT(k1, (k1p << 3) + e)];
        fft8_dif(b);
#pragma unroll
        for (int j = 0; j < 8; ++j) z[SLOT(k1, (k1p << 3) + j)] = b[j];
    }
    __syncthreads();

    // Hermitian unpack, iterated output-position-major (coalesced writes)
    const float sc = 0.5f / (float)N_FFT;   // fold in ifft 1/N
#pragma unroll
    for (int v = 0; v < 16; ++v) {
        int p = tid + (v << 8);                 // f2 position in [0,4096)
        int q   = p >> 9;
        int rem = p & 511;
        int t_  = rem >> 1, e = rem & 1;
        int j_  = (q << 1) + e;
        int kp  = (t_ >> 4) + ((t_ & 15) << 4) + (BREV4[j_] << 8);
#pragma unroll
        for (int par = 0; par < 2; ++par) {
            int k  = 2 * kp + par;
            int km = (N_FFT - k) & (N_FFT - 1);
            float2 A = z[ZADDR(k)];
            float2 B = z[ZADDR(km)];
            float2 Bj = make_float2(B.x, -B.y);
            float2 T0 = make_float2((A.x + Bj.x) * sc, (A.y + Bj.y) * sc);
            float2 dd = csub(A, Bj);
            float2 T1 = make_float2(dd.y * sc, -dd.x * sc);
            Tc[(size_t)d0 * N_FFT + (par << 12) + p] = T0;
            Tc[(size_t)d1 * N_FFT + (par << 12) + p] = T1;
        }
    }
}

// ---------------------------------------------------------------- main conv --
// One 512-thread block per channel d. Lower 256 threads: even-bin chain;
// upper 256: odd-bin chain, in two 32 KB LDS halves. NO persistent x register
// copy (live set ~60 VGPRs -> no scratch spills); each chain reloads its
// (L2-hot) row. launch_bounds min-waves lowered so the allocator has >=128
// VGPR headroom instead of spilling to satisfy a 64-reg occupancy target.
__global__ __launch_bounds__(512, 2) void conv5_kernel(float2* __restrict__ xoT,
                                                       const float2* __restrict__ tw,
                                                       const float2* __restrict__ Tc) {
    __shared__ float2 z[2 * SEQ];      // 64 KB: [par][16 rows][256 cols]
    const int tid = threadIdx.x;
    const int par = tid >> 8;          // chain parity (thread half)
    const int t   = tid & 255;         // local lane within chain
    const int d   = blockIdx.x;
    float2* zb = z + (par << 12);

    float2 a[16];

#pragma unroll
    for (int pb = 0; pb < 2; ++pb) {
        if (pb == 1) __syncthreads();    // combine-reads done before reuse
        const float2* xp = xoT + ((size_t)(pb * NCH + d) << 12);

        // ---- stage A: load row (+modulate for odd chain), fft16, twiddle
        if (par == 0) {
#pragma unroll
            for (int n1 = 0; n1 < 16; ++n1)
                a[n1] = xp[(n1 << 8) + t];
        } else {
#pragma unroll
            for (int n1 = 0; n1 < 16; ++n1)
                a[n1] = cmul(xp[(n1 << 8) + t], tw[(n1 << 8) + t]);
        }
        fft16_dif(a);
        {
            float2 w = tw[2 * t];        // W_4096^t
            float2 w2 = cmul(w, w);
            float2 we = make_float2(1.f, 0.f), wo = w;
#pragma unroll
            for (int k1 = 0; k1 < 16; k1 += 2) {
                zb[SLOT16(k1, t)]     = (k1 == 0) ? a[0] : cmul(a[BREV4[k1]], we);
                zb[SLOT16(k1 + 1, t)] = cmul(a[BREV4[k1 + 1]], wo);
                we = cmul(we, w2); wo = cmul(wo, w2);
            }
        }
        __syncthreads();                 // A writes are cross-wave

        // ---- stage B: FFT16 over n2 for (k1, n3)
        {
            const int k1 = t >> 4, n3 = t & 15;
#pragma unroll
            for (int n2 = 0; n2 < 16; ++n2)
                a[n2] = zb[SLOT16(k1, (n2 << 4) + n3)];
            fft16_dif(a);
            float2 wb = tw[n3 << 5];     // W_256^{n3}
            float2 wb2 = cmul(wb, wb);
            float2 be = make_float2(1.f, 0.f), bo = wb;
#pragma unroll
            for (int r1 = 0; r1 < 16; r1 += 2) {
                zb[SLOT16(k1, (r1 << 4) + n3)]       = (r1 == 0) ? a[0] : cmul(a[BREV4[r1]], be);
                zb[SLOT16(k1, ((r1 + 1) << 4) + n3)] = cmul(a[BREV4[r1 + 1]], bo);
                be = cmul(be, wb2); bo = cmul(bo, wb2);
            }
        }
        // B->C exchange stays inside tids [16*k1, 16*k1+15] (one wave)
        __builtin_amdgcn_sched_barrier(0);

        // ---- stage C fwd + pointwise (own parity plane) + stage C inverse
        {
            const int k1 = t >> 4, r1 = t & 15;
#pragma unroll
            for (int n3 = 0; n3 < 16; ++n3)
                a[n3] = zb[SLOT16(k1, (r1 << 4) + n3)];
            fft16_dif(a);
            const float4* tp = (const float4*)(Tc + ((size_t)d << 13) + (par << 12));
#pragma unroll
            for (int q = 0; q < 8; ++q) {
                float4 f4 = tp[(q << 8) + t];       // 16B/lane contiguous
                a[2 * q]     = cmul(a[2 * q],     make_float2(f4.x, f4.y));
                a[2 * q + 1] = cmul(a[2 * q + 1], make_float2(f4.z, f4.w));
            }
            ifft16_dit(a);               // DIF output order == DIT input order
#pragma unroll
            for (int n3 = 0; n3 < 16; ++n3)
                zb[SLOT16(k1, (r1 << 4) + n3)] = a[n3];
        }
        __builtin_amdgcn_sched_barrier(0);   // C->Binv: same 16-lane group

        // ---- stage B inverse
        {
            const int k1 = t >> 4, n3 = t & 15;
            float2 wb = tw[n3 << 5], wb2 = cmul(wb, wb);
            float2 be = make_float2(1.f, 0.f), bo = wb;
#pragma unroll
            for (int r1 = 0; r1 < 16; r1 += 2) {
                float2 v0 = zb[SLOT16(k1, (r1 << 4) + n3)];
                float2 v1 = zb[SLOT16(k1, ((r1 + 1) << 4) + n3)];
                a[BREV4[r1]]     = (r1 == 0) ? v0 : cmulj(v0, be);
                a[BREV4[r1 + 1]] = cmulj(v1, bo);
                be = cmul(be, wb2); bo = cmul(bo, wb2);
            }
            ifft16_dit(a);
#pragma unroll
            for (int n2 = 0; n2 < 16; ++n2)
                zb[SLOT16(k1, (n2 << 4) + n3)] = a[n2];
        }
        __syncthreads();                 // Binv writes read cross-wave by Ainv

        // ---- stage A inverse (thread-private column slots)
        {
            float2 w = tw[2 * t], w2 = cmul(w, w);
            float2 we = make_float2(1.f, 0.f), wo = w;
#pragma unroll
            for (int k1 = 0; k1 < 16; k1 += 2) {
                float2 v0 = zb[SLOT16(k1, t)];
                float2 v1 = zb[SLOT16(k1 + 1, t)];
                a[BREV4[k1]]     = (k1 == 0) ? v0 : cmulj(v0, we);
                a[BREV4[k1 + 1]] = cmulj(v1, wo);
                we = cmul(we, w2); wo = cmul(wo, w2);
            }
            ifft16_dit(a);               // a[n1] = U_par[n1*256 + t]
        }
        __syncthreads();                 // all A-inv reads done before overwrite

        // ---- half exchange: par0 exports n1=8..15, par1 exports n1=0..7
        if (par == 0) {
#pragma unroll
            for (int n1 = 8; n1 < 16; ++n1)
                zb[((n1 - 8) << 8) + t] = a[n1];
        } else {
#pragma unroll
            for (int n1 = 0; n1 < 8; ++n1)
                zb[(n1 << 8) + t] = a[n1];
        }
        __syncthreads();

        // ---- combine o[n] = U_e[n] + conj(w[n])*U_o[n]; each half stores 8
        {
            float2* xw = xoT + ((size_t)(pb * NCH + d) << 12);
            if (par == 0) {
#pragma unroll
                for (int n1 = 0; n1 < 8; ++n1) {
                    int n = (n1 << 8) + t;
                    float2 uo = z[SEQ + (n1 << 8) + t];
                    xw[n] = cadd(a[n1], cmulj(uo, tw[n]));
                }
            } else {
#pragma unroll
                for (int n1 = 8; n1 < 16; ++n1) {
                    int n = (n1 << 8) + t;
                    float2 ue = z[((n1 - 8) << 8) + t];
                    xw[n] = cadd(ue, cmulj(a[n1], tw[n]));
                }
            }
        }
    }
}

// ---------------------------------------------------------------- transpose --
// oT[pb][d][n] (float2: {b=2pb, b=2pb+1}) -> out[b][n][d]. LDS-tiled 32d x 64n.
__global__ __launch_bounds__(256) void transpose_out(const float2* __restrict__ oT,
                                                     float* __restrict__ out) {
    __shared__ float2 tile[32][65];
    const int tid = threadIdx.x;
    const int bid = blockIdx.x;
    const int pb = bid >> 10;
    const int dt = (bid >> 6) & 15;
    const int nt = bid & 63;
    const int d0 = dt << 5, n0 = nt << 6;

    {
        const int nl = tid & 63, dl = tid >> 6;
#pragma unroll
        for (int i = 0; i < 8; ++i) {
            int dd = dl + (i << 2);
            tile[dd][nl] = oT[(((size_t)(pb * NCH + d0 + dd)) << 12) + n0 + nl];
        }
    }
    __syncthreads();
    {
        const int dl = tid & 31, ns = tid >> 5;
        float* o0 = out + (size_t)(2 * pb) * SEQ * NCH;
        float* o1 = o0 + (size_t)SEQ * NCH;
#pragma unroll
        for (int j = 0; j < 8; ++j) {
            int nn = n0 + ns + (j << 3);
            float2 v = tile[dl][ns + (j << 3)];
            o0[(size_t)nn * NCH + d0 + dl] = v.x;
            o1[(size_t)nn * NCH + d0 + dl] = v.y;
        }
    }
}

// =================== fallback path (small ws) ===============================
__global__ __launch_bounds__(256) void tfft2_kernel(const float* __restrict__ t,
                                                    const float2* __restrict__ tw,
                                                    float2* __restrict__ Tc) {
    __shared__ float2 z[N_FFT];
    const int tid = threadIdx.x;
    const int d0 = blockIdx.x * 2;
    const int d1 = d0 + 1;

    float2 a[32];
#pragma unroll
    for (int n1 = 0; n1 < 32; ++n1) {
        int n = (n1 << 8) + tid;
        float va = 0.f, vb = 0.f;
        if (n < TLEN) {
            va = t[(size_t)n * NCH + d0];
            vb = t[(size_t)n * NCH + d1];
        }
        a[n1] = make_float2(va, vb);
    }
    fft32_dif(a);
    {
        float2 w = tw[tid], w2 = cmul(w, w);
        float2 we = make_float2(1.f, 0.f), wo = w;
#pragma unroll
        for (int k1 = 0; k1 < 32; k1 += 2) {
            z[SLOT(k1, tid)]     = (k1 == 0) ? a[0] : cmul(a[BREV5[k1]], we);
            z[SLOT(k1 + 1, tid)] = cmul(a[BREV5[k1 + 1]], wo);
            we = cmul(we, w2); wo = cmul(wo, w2);
        }
    }
    __syncthreads();
    {
        const int r = tid >> 3, n2p = tid & 7;
#pragma unroll
        for (int n1p = 0; n1p < 32; ++n1p)
            a[n1p] = z[SLOT(r, (n1p << 3) + n2p)];
        fft32_dif(a);
        float2 wb = tw[n2p << 5], wb2 = cmul(wb, wb);
        float2 be = make_float2(1.f, 0.f), bo = wb;
#pragma unroll
        for (int k1p = 0; k1p < 32; k1p += 2) {
            z[SLOT(r, (k1p << 3) + n2p)]       = (k1p == 0) ? a[0] : cmul(a[BREV5[k1p]], be);
            z[SLOT(r, ((k1p + 1) << 3) + n2p)] = cmul(a[BREV5[k1p + 1]], bo);
            be = cmul(be, wb2); bo = cmul(bo, wb2);
        }
    }
    __syncthreads();
#pragma unroll
    for (int u = 0; u < 4; ++u) {
        int f = tid + (u << 8);
        int k1 = f >> 5, k1p = f & 31;
        float2 b[8];
#pragma unroll
        for (int e = 0; e < 8; ++e) b[e] = z[SLOT(k1, (k1p << 3) + e)];
        fft8_dif(b);
#pragma unroll
        for (int j = 0; j < 8; ++j) z[SLOT(k1, (k1p << 3) + j)] = b[j];
    }
    __syncthreads();

    const float sc = 0.5f / (float)N_FFT;
#pragma unroll
    for (int v = 0; v < 16; ++v) {
        int s = tid + (v << 8);
        int k1 = s >> 8, r1 = (s >> 4) & 15, j = s & 15;
        int kp = k1 + (r1 << 4) + (BREV4[j] << 8);
#pragma unroll
        for (int par = 0; par < 2; ++par) {
            int k  = 2 * kp + par;
            int km = (N_FFT - k) & (N_FFT - 1);
            float2 A = z[ZADDR(k)];
            float2 B = z[ZADDR(km)];
            float2 Bj = make_float2(B.x, -B.y);
            float2 T0 = make_float2((A.x + Bj.x) * sc, (A.y + Bj.y) * sc);
            float2 dd = csub(A, Bj);
            float2 T1 = make_float2(dd.y * sc, -dd.x * sc);
            Tc[(size_t)d0 * N_FFT + (par << 12) + s] = T0;
            Tc[(size_t)d1 * N_FFT + (par << 12) + s] = T1;
        }
    }
}

template<bool OT>
__global__ __launch_bounds__(256, 2) void conv3_kernel(const float* __restrict__ x,
                                                       const float2* __restrict__ tw,
                                                       const float2* __restrict__ Tc,
                                                       float2* __restrict__ oT,
                                                       float* __restrict__ out) {
    __shared__ float2 z[SEQ];
    const int tid = threadIdx.x;
    const int sb = (blockIdx.x & 7) * 128 + (blockIdx.x >> 3);
    const int d  = sb >> 1;
    const int pb = sb & 1;

    const float* x0 = x + (size_t)(2 * pb) * SEQ * NCH + d;
    const float* x1 = x0 + (size_t)SEQ * NCH;

    float2 a[16], ie[16];

#pragma unroll
    for (int par = 0; par < 2; ++par) {
        if (par == 1) __syncthreads();

        if (par == 0) {
#pragma unroll
            for (int n1 = 0; n1 < 16; ++n1) {
                int n = (n1 << 8) + tid;
                a[n1] = make_float2(x0[(size_t)n * NCH], x1[(size_t)n * NCH]);
            }
        } else {
#pragma unroll
            for (int n1 = 0; n1 < 16; ++n1) {
                int n = (n1 << 8) + tid;
                float2 v = make_float2(x0[(size_t)n * NCH], x1[(size_t)n * NCH]);
                a[n1] = cmul(v, tw[n]);
            }
        }
        fft16_dif(a);
        {
            float2 w = tw[2 * tid], w2 = cmul(w, w);
            float2 we = make_float2(1.f, 0.f), wo = w;
#pragma unroll
            for (int k1 = 0; k1 < 16; k1 += 2) {
                z[SLOT16(k1, tid)]     = (k1 == 0) ? a[0] : cmul(a[BREV4[k1]], we);
                z[SLOT16(k1 + 1, tid)] = cmul(a[BREV4[k1 + 1]], wo);
                we = cmul(we, w2); wo = cmul(wo, w2);
            }
        }
        __syncthreads();
        {
            const int k1 = tid >> 4, n3 = tid & 15;
#pragma unroll
            for (int n2 = 0; n2 < 16; ++n2)
                a[n2] = z[SLOT16(k1, (n2 << 4) + n3)];
            fft16_dif(a);
            float2 wb = tw[n3 << 5], wb2 = cmul(wb, wb);
            float2 be = make_float2(1.f, 0.f), bo = wb;
#pragma unroll
            for (int r1 = 0; r1 < 16; r1 += 2) {
                z[SLOT16(k1, (r1 << 4) + n3)]       = (r1 == 0) ? a[0] : cmul(a[BREV4[r1]], be);
                z[SLOT16(k1, ((r1 + 1) << 4) + n3)] = cmul(a[BREV4[r1 + 1]], bo);
                be = cmul(be, wb2); bo = cmul(bo, wb2);
            }
        }
        __syncthreads();
        {
            const int k1 = tid >> 4, r1 = tid & 15;
#pragma unroll
            for (int n3 = 0; n3 < 16; ++n3)
                a[n3] = z[SLOT16(k1, (r1 << 4) + n3)];
            fft16_dif(a);
            const float2* Td = Tc + ((size_t)d << 13) + (par << 12);
#pragma unroll
            for (int j = 0; j < 16; ++j) {
                // compact per-thread layout fallback (legacy order)
                float2 T = Td[(tid << 4) + j];
                a[j] = cmul(a[j], T);
            }
            ifft16_dit(a);
#pragma unroll
            for (int n3 = 0; n3 < 16; ++n3)
                z[SLOT16(k1, (r1 << 4) + n3)] = a[n3];
        }
        __syncthreads();
        {
            const int k1 = tid >> 4, n3 = tid & 15;
            float2 wb = tw[n3 << 5], wb2 = cmul(wb, wb);
            float2 be = make_float2(1.f, 0.f), bo = wb;
#pragma unroll
            for (int r1 = 0; r1 < 16; r1 += 2) {
                float2 v0 = z[SLOT16(k1, (r1 << 4) + n3)];
                float2 v1 = z[SLOT16(k1, ((r1 + 1) << 4) + n3)];
                a[BREV4[r1]]     = (r1 == 0) ? v0 : cmulj(v0, be);
                a[BREV4[r1 + 1]] = cmulj(v1, bo);
                be = cmul(be, wb2); bo = cmul(bo, wb2);
            }
            ifft16_dit(a);
#pragma unroll
            for (int n2 = 0; n2 < 16; ++n2)
                z[SLOT16(k1, (n2 << 4) + n3)] = a[n2];
        }
        __syncthreads();
        {
            float2 w = tw[2 * tid], w2 = cmul(w, w);
            float2 we = make_float2(1.f, 0.f), wo = w;
#pragma unroll
            for (int k1 = 0; k1 < 16; k1 += 2) {
                float2 v0 = z[SLOT16(k1, tid)];
                float2 v1 = z[SLOT16(k1 + 1, tid)];
                a[BREV4[k1]]     = (k1 == 0) ? v0 : cmulj(v0, we);
                a[BREV4[k1 + 1]] = cmulj(v1, wo);
                we = cmul(we, w2); wo = cmul(wo, w2);
            }
            ifft16_dit(a);
        }

        if (par == 0) {
#pragma unroll
            for (int n1 = 0; n1 < 16; ++n1) ie[n1] = a[n1];
        } else {
            if constexpr (OT) {
                float2* op = oT + (((size_t)(pb * NCH + d)) << 12);
#pragma unroll
                for (int n1 = 0; n1 < 16; ++n1) {
                    int n = (n1 << 8) + tid;
                    op[n] = cadd(ie[n1], cmulj(a[n1], tw[n]));
                }
            } else {
                float* o0 = out + (size_t)(2 * pb) * SEQ * NCH + d;
                float* o1 = o0 + (size_t)SEQ * NCH;
#pragma unroll
                for (int n1 = 0; n1 < 16; ++n1) {
                    int n = (n1 << 8) + tid;
                    float2 o = cadd(ie[n1], cmulj(a[n1], tw[n]));
                    o0[(size_t)n * NCH] = o.x;
                    o1[(size_t)n * NCH] = o.y;
                }
            }
        }
    }
}

extern "C" void kernel_launch(void* const* d_in, const int* in_sizes, int n_in,
                              void* d_out, int out_size, void* d_ws, size_t ws_size,
                              hipStream_t stream) {
    (void)in_sizes; (void)n_in; (void)out_size;
    const float* x = (const float*)d_in[0];
    const float* t = (const float*)d_in[1];
    float* out = (float*)d_out;

    float2* tw  = (float2*)d_ws;                   // 8192 f2 = 64 KB
    float2* Tc  = tw + N_FFT;                      // 512*8192 f2 = 33.55 MB
    float2* xoT = Tc + (size_t)NCH * N_FFT;        // 2*512*4096 f2 = 33.55 MB
    float2* tT  = xoT + 2ull * NCH * SEQ;          // 256*8192 f2 = 16.78 MB

    const size_t need_full = sizeof(float2) * ((size_t)N_FFT + (size_t)NCH * N_FFT
                                               + 2ull * NCH * SEQ
                                               + 256ull * N_FFT);   // ~84 MB
    const size_t need_ot   = sizeof(float2) * ((size_t)N_FFT + (size_t)NCH * N_FFT
                                               + 2ull * NCH * SEQ); // ~67.2 MB

    twiddle_init<<<N_FFT / 256, 256, 0, stream>>>(tw);
    if (ws_size >= need_full) {
        transpose_in<<<1536, 256, 0, stream>>>(x, t, xoT, tT);
        tfft3_kernel<<<NCH / 2, 256, 0, stream>>>(tT, tw, Tc);
        conv5_kernel<<<NCH, 512, 0, stream>>>(xoT, tw, Tc);
        transpose_out<<<2048, 256, 0, stream>>>(xoT, out);
    } else if (ws_size >= need_ot) {
        tfft2_kernel<<<NCH / 2, 256, 0, stream>>>(t, tw, Tc);
        conv3_kernel<true><<<1024, 256, 0, stream>>>(x, tw, Tc, xoT, out);
        transpose_out<<<2048, 256, 0, stream>>>(xoT, out);
    } else {
        tfft2_kernel<<<NCH / 2, 256, 0, stream>>>(t, tw, Tc);
        conv3_kernel<false><<<1024, 256, 0, stream>>>(x, tw, Tc, nullptr, out);
    }
}